// Round 14
// baseline (375.195 us; speedup 1.0000x reference)
//
#include <hip/hip_runtime.h>

#define NE_N 50000
#define NP_N 25000
#define E_N 200000
#define DIM 128
#define LOG2E 1.4426950408889634f
#define NREP 1024  // csum replicas

// rank build: 32 chunks/type, LDS hash per chunk -> zero device atomics
#define NCHK 32
#define CHK_E (E_N / NCHK)  // 6250
#define TBL 16384           // hash slots; load factor 6250/16384 = 0.38

// degree-sort (gat wave balance): counting sort, 64 bins
#define NBIN 64
#define EB49 ((NE_N + 1023) / 1024)  // 49
#define PB25 ((NP_N + 1023) / 1024)  // 25

typedef __attribute__((ext_vector_type(8))) short short8;
typedef __attribute__((ext_vector_type(4))) float f32x4;
typedef __attribute__((ext_vector_type(2))) float f32x2;

static __device__ __forceinline__ ushort f2bf(float f) {
  unsigned x = __float_as_uint(f);
  return (ushort)((x + 0x7fffu + ((x >> 16) & 1u)) >> 16);  // RNE
}
static __device__ __forceinline__ float bf2f(ushort u) {
  return __uint_as_float(((unsigned)u) << 16);
}

// async global->LDS, 16B/lane; LDS dest is WAVE-UNIFORM base + lane*16.
static __device__ __forceinline__ void gload_lds16(const void* g, void* l) {
  __builtin_amdgcn_global_load_lds(
      (const __attribute__((address_space(1))) void*)g,
      (__attribute__((address_space(3))) void*)l, 16, 0, 0);
}

// ---------------------------------------------------------------------------
// Fused: per-chunk LDS-hash rank build (128 blk) | conv_w (12) | vec (3).
// hh is CHUNK-MAJOR uchar h[c*N + node] (counts <= max degree ~30 << 255).
#define HIST_BLKS (4 * NCHK)            // 128
#define HS_TOT (HIST_BLKS + 12 + 3)     // +conv_w +vec
__global__ __launch_bounds__(512) void hist_setup_k(
    const float* __restrict__ W_src, const float* __restrict__ W_dst,
    const float* __restrict__ att_dst, ushort* __restrict__ WbT,
    float* __restrict__ vec, const int* __restrict__ d0,
    const int* __restrict__ d1, const int* __restrict__ d2,
    const int* __restrict__ d3, unsigned char* __restrict__ h0,
    unsigned char* __restrict__ h1, unsigned char* __restrict__ h2,
    unsigned char* __restrict__ h3, ushort* __restrict__ rk0,
    ushort* __restrict__ rk1, ushort* __restrict__ rk2,
    ushort* __restrict__ rk3) {
  __shared__ int keys[TBL];
  __shared__ int cnts[TBL];
  const int blk = blockIdx.x;
  const int tid = threadIdx.x;
  if (blk < HIST_BLKS) {
    const int ty = blk >> 5, c = blk & (NCHK - 1);
    const int NN = (ty == 0 || ty == 3) ? NE_N : NP_N;
    const int* dst = ty == 0 ? d0 : ty == 1 ? d1 : ty == 2 ? d2 : d3;
    unsigned char* h = ty == 0 ? h0 : ty == 1 ? h1 : ty == 2 ? h2 : h3;
    ushort* rk = ty == 0 ? rk0 : ty == 1 ? rk1 : ty == 2 ? rk2 : rk3;
    for (int i = tid; i < TBL; i += 512) { keys[i] = -1; cnts[i] = 0; }
    __syncthreads();
    const int base = c * CHK_E;
    for (int i = tid; i < CHK_E; i += 512) {
      const int e = base + i;
      const int d = dst[e];
      unsigned hsh = ((unsigned)d * 2654435761u) >> 18;
      hsh &= (TBL - 1);
      int lr;
      while (true) {
        int prev = atomicCAS(&keys[hsh], -1, d);
        if (prev == -1 || prev == d) { lr = atomicAdd(&cnts[hsh], 1); break; }
        hsh = (hsh + 1) & (TBL - 1);
      }
      rk[e] = (ushort)lr;
    }
    __syncthreads();
    for (int i = tid; i < TBL; i += 512) {
      int k = keys[i];
      if (k >= 0) h[(size_t)c * NN + k] = (unsigned char)cnts[i];
    }
  } else if (blk < HIST_BLKS + 12) {
    const int w = blk - HIST_BLKS;
    const float* src = W_src + (size_t)w * DIM * DIM;
    ushort* dstw = WbT + (size_t)w * DIM * DIM;
    for (int i = tid; i < DIM * DIM; i += 512) {
      int k = i >> 7, n = i & 127;
      dstw[n * DIM + k] = f2bf(src[i]);
    }
  } else {
    const int b = blk - HIST_BLKS - 12;
    const int lt = b * 4 + (tid >> 7);
    const int i = tid & 127;
    const float* Wd = W_dst + (size_t)lt * DIM * DIM;
    const float* ad = att_dst + lt * DIM;
    float s = 0.f;
#pragma unroll 8
    for (int j = 0; j < DIM; j++) s += Wd[i * DIM + j] * ad[j];
    vec[lt * DIM + i] = s;
  }
}

// ---------------------------------------------------------------------------
// CSR scan. scanA: chunk-major uchar h -> 32 coalesced 4B passes per node
// group; in-place exclusive prefix over chunks; emit cnt=degree + block sums.
__global__ __launch_bounds__(256) void scanA_k(
    unsigned char* __restrict__ h0, unsigned char* __restrict__ h1,
    unsigned char* __restrict__ h2, unsigned char* __restrict__ h3,
    int* __restrict__ c0, int* __restrict__ c1, int* __restrict__ c2,
    int* __restrict__ c3, int* __restrict__ part) {
  int ty = blockIdx.y;
  unsigned char* h = ty == 0 ? h0 : ty == 1 ? h1 : ty == 2 ? h2 : h3;
  int* cnt = ty == 0 ? c0 : ty == 1 ? c1 : ty == 2 ? c2 : c3;
  int n = (ty == 0 || ty == 3) ? NE_N : NP_N;  // both divisible by 4
  int nblk = (n + 1023) >> 10;
  if ((int)blockIdx.x >= nblk) return;
  int base = blockIdx.x * 1024 + threadIdx.x * 4;
  int s = 0;
  if (base < n) {
    int run0 = 0, run1 = 0, run2 = 0, run3 = 0;
#pragma unroll
    for (int c = 0; c < NCHK; c++) {
      unsigned* hp = (unsigned*)(h + (size_t)c * n + base);
      unsigned v = *hp;
      *hp = (unsigned)(run0 & 255) | ((unsigned)(run1 & 255) << 8) |
            ((unsigned)(run2 & 255) << 16) | ((unsigned)(run3 & 255) << 24);
      run0 += (int)(v & 255u);
      run1 += (int)((v >> 8) & 255u);
      run2 += (int)((v >> 16) & 255u);
      run3 += (int)((v >> 24) & 255u);
    }
    cnt[base + 0] = run0; cnt[base + 1] = run1;
    cnt[base + 2] = run2; cnt[base + 3] = run3;
    s = run0 + run1 + run2 + run3;
  }
  int lane = threadIdx.x & 63, wid = threadIdx.x >> 6;
#pragma unroll
  for (int off = 32; off > 0; off >>= 1) s += __shfl_xor(s, off, 64);
  __shared__ int ws4[4];
  if (lane == 0) ws4[wid] = s;
  __syncthreads();
  if (threadIdx.x == 0)
    part[ty * 64 + blockIdx.x] = ws4[0] + ws4[1] + ws4[2] + ws4[3];
}

__global__ __launch_bounds__(256) void scanBC_k(
    const int* __restrict__ c0, const int* __restrict__ c1,
    const int* __restrict__ c2, const int* __restrict__ c3,
    int* __restrict__ r0, int* __restrict__ r1, int* __restrict__ r2,
    int* __restrict__ r3, const int* __restrict__ part) {
  int ty = blockIdx.y;
  int bx = blockIdx.x;
  const int* cnt = ty == 0 ? c0 : ty == 1 ? c1 : ty == 2 ? c2 : c3;
  int* rp = ty == 0 ? r0 : ty == 1 ? r1 : ty == 2 ? r2 : r3;
  int n = (ty == 0 || ty == 3) ? NE_N : NP_N;
  int nblk = (n + 1023) >> 10;
  if (bx >= nblk) return;

  __shared__ int s_excl;
  if (threadIdx.x < 64) {
    int pl = threadIdx.x;
    int v = (pl < nblk) ? part[ty * 64 + pl] : 0;
    int sc = v;
#pragma unroll
    for (int off = 1; off < 64; off <<= 1) {
      int t = __shfl_up(sc, off, 64);
      if (pl >= off) sc += t;
    }
    if (pl == bx) s_excl = sc - v;
  }
  if (bx == 0 && threadIdx.x == 0) rp[n] = E_N;  // total is always E_N
  __syncthreads();

  int base = bx * 1024 + threadIdx.x * 4;
  int v[4];
#pragma unroll
  for (int j = 0; j < 4; j++) v[j] = (base + j < n) ? cnt[base + j] : 0;
  int s = v[0] + v[1] + v[2] + v[3];
  int lane = threadIdx.x & 63, wid = threadIdx.x >> 6;
  int sc = s;
#pragma unroll
  for (int off = 1; off < 64; off <<= 1) {
    int t = __shfl_up(sc, off, 64);
    if (lane >= off) sc += t;
  }
  __shared__ int ws4[4];
  if (lane == 63) ws4[wid] = sc;
  __syncthreads();
  int wbase = 0;
  for (int w = 0; w < wid; w++) wbase += ws4[w];
  int p = s_excl + wbase + sc - s;
#pragma unroll
  for (int j = 0; j < 4; j++) {
    if (base + j < n) rp[base + j] = p;
    p += v[j];
  }
}

// ---------------------------------------------------------------------------
// Degree sort (counting, 64 bins): nodes of each dst-type ordered by total
// degree (degA+degB) so gat waves get 4 equal-degree nodes. gat iterates
// max(8 stream lengths)/wave: Poisson streams -> E[max] ~2x mean (194K vs
// 100K wave-iters). Sorted: max ~= mean. Any node order is valid (per-node
// math independent; csum order already atomic-nondeterministic).
__global__ __launch_bounds__(256) void sortA_k(
    const int* __restrict__ rp0, const int* __restrict__ rp3,
    const int* __restrict__ rp1, const int* __restrict__ rp2,
    unsigned* __restrict__ bh) {
  const int ty = blockIdx.y;
  const int n = ty ? NP_N : NE_N;
  const int nblk = ty ? PB25 : EB49;
  if ((int)blockIdx.x >= nblk) return;
  const int* rpA = ty ? rp1 : rp0;
  const int* rpB = ty ? rp2 : rp3;
  __shared__ unsigned h[NBIN];
  if (threadIdx.x < NBIN) h[threadIdx.x] = 0;
  __syncthreads();
  const int base = blockIdx.x * 1024 + threadIdx.x * 4;
#pragma unroll
  for (int j = 0; j < 4; j++) {
    const int node = base + j;
    if (node < n) {
      int key = (rpA[node + 1] - rpA[node]) + (rpB[node + 1] - rpB[node]);
      if (key > NBIN - 1) key = NBIN - 1;
      atomicAdd(&h[key], 1u);
    }
  }
  __syncthreads();
  if (threadIdx.x < NBIN)
    bh[((size_t)ty * NBIN + threadIdx.x) * EB49 + blockIdx.x] = h[threadIdx.x];
}

__global__ __launch_bounds__(256) void sortB_k(const unsigned* __restrict__ bh,
                                               unsigned* __restrict__ off) {
  __shared__ unsigned tot[NBIN];
  __shared__ unsigned binoff[NBIN];
  const int tid = threadIdx.x;
  for (int ty = 0; ty < 2; ty++) {
    const int nblk = ty ? PB25 : EB49;
    if (tid < NBIN) {
      unsigned s = 0;
      for (int b = 0; b < nblk; b++)
        s += bh[((size_t)ty * NBIN + tid) * EB49 + b];
      tot[tid] = s;
    }
    __syncthreads();
    if (tid == 0) {
      unsigned r = 0;
      for (int k = 0; k < NBIN; k++) { binoff[k] = r; r += tot[k]; }
    }
    __syncthreads();
    if (tid < NBIN) {
      unsigned r = binoff[tid];
      for (int b = 0; b < nblk; b++) {
        off[((size_t)ty * NBIN + tid) * EB49 + b] = r;
        r += bh[((size_t)ty * NBIN + tid) * EB49 + b];
      }
    }
    __syncthreads();
  }
}

__global__ __launch_bounds__(256) void sortC_k(
    const int* __restrict__ rp0, const int* __restrict__ rp3,
    const int* __restrict__ rp1, const int* __restrict__ rp2,
    const unsigned* __restrict__ off, int* __restrict__ permE,
    int* __restrict__ permP) {
  const int ty = blockIdx.y;
  const int n = ty ? NP_N : NE_N;
  const int nblk = ty ? PB25 : EB49;
  if ((int)blockIdx.x >= nblk) return;
  const int* rpA = ty ? rp1 : rp0;
  const int* rpB = ty ? rp2 : rp3;
  int* perm = ty ? permP : permE;
  __shared__ unsigned cur[NBIN];
  if (threadIdx.x < NBIN)
    cur[threadIdx.x] =
        off[((size_t)ty * NBIN + threadIdx.x) * EB49 + blockIdx.x];
  __syncthreads();
  const int base = blockIdx.x * 1024 + threadIdx.x * 4;
#pragma unroll
  for (int j = 0; j < 4; j++) {
    const int node = base + j;
    if (node < n) {
      int key = (rpA[node + 1] - rpA[node]) + (rpB[node + 1] - rpB[node]);
      if (key > NBIN - 1) key = NBIN - 1;
      const unsigned pos = atomicAdd(&cur[key], 1u);
      perm[pos] = node;
    }
  }
}

// ---------------------------------------------------------------------------
// GEMM: 8-wave (512-thr) blocks, 128 rows/block, W staged via global_load_lds.
#define EBLK ((NE_N + 127) / 128)     // 391
#define PBLK ((NP_N + 127) / 128)     // 196
#define GEMM_BLK (EBLK + PBLK)        // 587
#define FILL_PER_CHK 13               // ceil(6250/512)
#define FILL_BLKS (4 * NCHK * FILL_PER_CHK)  // 1664
#define HG2_TOT (GEMM_BLK + FILL_BLKS)       // 2251

template <bool FP32>
static __device__ __forceinline__ void x_prefetch(
    const void* xb, int rowA, int quad, float4* xraw, short8* xvv) {
  if (FP32) {
    const float* xf32 = (const float*)xb + (size_t)rowA * DIM + quad * 8;
#pragma unroll
    for (int k0 = 0; k0 < 4; k0++) {
      xraw[2 * k0] = *(const float4*)(xf32 + k0 * 32);
      xraw[2 * k0 + 1] = *(const float4*)(xf32 + k0 * 32 + 4);
    }
  } else {
    const ushort* xb16 = (const ushort*)xb + (size_t)rowA * DIM + quad * 8;
#pragma unroll
    for (int k0 = 0; k0 < 4; k0++)
      xvv[k0] = *(const short8*)(xb16 + k0 * 32);
  }
}

template <bool FP32>
static __device__ __forceinline__ void strip_body(
    int row0, int N, int m, int quad, int lane, const short8* wlds,
    const float* dv0, const float* dv1, const float* a0, const float* a1,
    unsigned char* hs0, unsigned char* hs1, float* es0, float* es1,
    float* edA, float* edB, float4* xraw, short8* xvv) {
  // ---- ed partials + bf16 pack ----
  float edp0 = 0.f, edp1 = 0.f;
#pragma unroll
  for (int k0 = 0; k0 < 4; k0++) {
    float xf[8];
    if (FP32) {
      float4 f0 = xraw[2 * k0], f1 = xraw[2 * k0 + 1];
      xf[0] = f0.x; xf[1] = f0.y; xf[2] = f0.z; xf[3] = f0.w;
      xf[4] = f1.x; xf[5] = f1.y; xf[6] = f1.z; xf[7] = f1.w;
      short8 xv;
#pragma unroll
      for (int j = 0; j < 8; j++) xv[j] = (short)f2bf(xf[j]);
      xvv[k0] = xv;
    } else {
#pragma unroll
      for (int j = 0; j < 8; j++) xf[j] = bf2f((ushort)xvv[k0][j]);
    }
    int off = k0 * 32 + quad * 8;
    float4 vA0 = *(const float4*)&dv0[off];
    float4 vA1 = *(const float4*)&dv0[off + 4];
    float4 vB0 = *(const float4*)&dv1[off];
    float4 vB1 = *(const float4*)&dv1[off + 4];
    edp0 += xf[0] * vA0.x + xf[1] * vA0.y + xf[2] * vA0.z + xf[3] * vA0.w +
            xf[4] * vA1.x + xf[5] * vA1.y + xf[6] * vA1.z + xf[7] * vA1.w;
    edp1 += xf[0] * vB0.x + xf[1] * vB0.y + xf[2] * vB0.z + xf[3] * vB0.w +
            xf[4] * vB1.x + xf[5] * vB1.y + xf[6] * vB1.z + xf[7] * vB1.w;
  }

  // ---- MFMA (LDS fragments, conflict-free linear) ----
  f32x4 acc0[8], acc1[8];
#pragma unroll
  for (int f = 0; f < 8; f++) {
    acc0[f] = (f32x4){0.f, 0.f, 0.f, 0.f};
    acc1[f] = (f32x4){0.f, 0.f, 0.f, 0.f};
  }
#pragma unroll
  for (int k0 = 0; k0 < 4; k0++) {
    const short8 xv = xvv[k0];
#pragma unroll
    for (int f = 0; f < 8; f++) {
      acc0[f] = __builtin_amdgcn_mfma_f32_16x16x32_bf16(
          wlds[(k0 * 8 + f) * 64 + lane], xv, acc0[f], 0, 0, 0);
      acc1[f] = __builtin_amdgcn_mfma_f32_16x16x32_bf16(
          wlds[2048 + (k0 * 8 + f) * 64 + lane], xv, acc1[f], 0, 0, 0);
    }
  }

  const int row = row0 + m;
  edp0 += __shfl_xor(edp0, 16, 64);
  edp0 += __shfl_xor(edp0, 32, 64);
  edp1 += __shfl_xor(edp1, 16, 64);
  edp1 += __shfl_xor(edp1, 32, 64);
  if (quad == 0 && row < N) {
    edA[row] = edp0 * LOG2E;
    edB[row] = edp1 * LOG2E;
  }

#pragma unroll
  for (int set = 0; set < 2; set++) {
    f32x4* acc = set ? acc1 : acc0;
    const float* as = set ? a1 : a0;
    float* es = set ? es1 : es0;
    unsigned char* hs = set ? hs1 : hs0;

    float esum = 0.f;
#pragma unroll
    for (int f = 0; f < 8; f++) {
      float4 av = *(const float4*)&as[f * 16 + quad * 4];
      esum += acc[f][0] * av.x + acc[f][1] * av.y + acc[f][2] * av.z +
              acc[f][3] * av.w;
    }
    esum += __shfl_xor(esum, 16, 64);
    esum += __shfl_xor(esum, 32, 64);
    if (quad == 0 && row < N) es[row] = esum * LOG2E;

    if (row < N) {
#pragma unroll
      for (int f = 0; f < 8; f++) {
        int w = __builtin_amdgcn_cvt_pk_fp8_f32(acc[f][0], acc[f][1], 0, false);
        w = __builtin_amdgcn_cvt_pk_fp8_f32(acc[f][2], acc[f][3], w, true);
        *(unsigned*)&hs[(size_t)row * DIM + f * 16 + quad * 4] = (unsigned)w;
      }
    }
  }
}

template <bool FP32>
static __device__ __forceinline__ void gemm_body(
    int blk, const void* __restrict__ xev, const void* __restrict__ xpv,
    const ushort* __restrict__ WbT, const float* __restrict__ att,
    const float* __restrict__ vec, int l, unsigned char* __restrict__ hsE0,
    unsigned char* __restrict__ hsE1, unsigned char* __restrict__ hsP3,
    unsigned char* __restrict__ hsP2, float* __restrict__ esE0,
    float* __restrict__ esE1, float* __restrict__ esP3,
    float* __restrict__ esP2, float* __restrict__ edEA,
    float* __restrict__ edEB, float* __restrict__ edPA,
    float* __restrict__ edPB) {
  const void* xb;
  const ushort *W0T, *W1T;
  const float *a0, *a1, *dv0, *dv1;
  unsigned char *hs0, *hs1;
  float *es0, *es1, *edA, *edB;
  int N, rbase;
  if (blk < EBLK) {
    xb = xev; N = NE_N; rbase = blk * 128;
    W0T = WbT + (size_t)(l * 4 + 0) * DIM * DIM;
    W1T = WbT + (size_t)(l * 4 + 1) * DIM * DIM;
    a0 = att + (l * 4 + 0) * DIM; a1 = att + (l * 4 + 1) * DIM;
    dv0 = vec + (l * 4 + 0) * DIM; dv1 = vec + (l * 4 + 3) * DIM;
    hs0 = hsE0; hs1 = hsE1; es0 = esE0; es1 = esE1;
    edA = edEA; edB = edEB;
  } else {
    blk -= EBLK; xb = xpv; N = NP_N; rbase = blk * 128;
    W0T = WbT + (size_t)(l * 4 + 3) * DIM * DIM;
    W1T = WbT + (size_t)(l * 4 + 2) * DIM * DIM;
    a0 = att + (l * 4 + 3) * DIM; a1 = att + (l * 4 + 2) * DIM;
    dv0 = vec + (l * 4 + 1) * DIM; dv1 = vec + (l * 4 + 2) * DIM;
    hs0 = hsP3; hs1 = hsP2; es0 = esP3; es1 = esP2;
    edA = edPA; edB = edPB;
  }

  const int wave = threadIdx.x >> 6;
  const int lane = threadIdx.x & 63;
  const int m = lane & 15, quad = lane >> 4;
  const int row0 = rbase + wave * 16;
  int rowL = row0 + m;
  if (rowL >= N) rowL = N - 1;  // clamp loads; stores guarded

  // ---- x prefetch (hides under W staging) ----
  float4 xraw[8]; short8 xvv[4];
  x_prefetch<FP32>(xb, rowL, quad, xraw, xvv);

  // ---- stage W0T,W1T into LDS via global_load_lds (uniform base+lane*16) --
  __shared__ short8 wlds[4096];  // 64KB: 2 sets x 4 k0 x 8 f x 64 lanes x 16B
  {
    const int i15 = lane & 15, i4 = lane >> 4;
#pragma unroll
    for (int r = 0; r < 8; r++) {
      const int g = r * 8 + wave;           // 0..63, each exactly once
      const int set = g >> 5, k0 = (g >> 3) & 3, f = g & 7;
      const ushort* WT = set ? W1T : W0T;
      gload_lds16(WT + (size_t)(f * 16 + i15) * DIM + k0 * 32 + i4 * 8,
                  &wlds[g * 64]);
    }
  }
  __syncthreads();
  if (row0 >= N) return;  // tail waves: staged + synced, no compute

  strip_body<FP32>(row0, N, m, quad, lane, wlds, dv0, dv1, a0, a1,
                   hs0, hs1, es0, es1, edA, edB, xraw, xvv);
}

// standalone gemm (layers 1,2 — bf16 input)
__global__ __launch_bounds__(512, 4) void gemm_k(
    const ushort* __restrict__ xe, const ushort* __restrict__ xp,
    const ushort* __restrict__ WbT, const float* __restrict__ att,
    const float* __restrict__ vec, int l, unsigned char* __restrict__ hsE0,
    unsigned char* __restrict__ hsE1, unsigned char* __restrict__ hsP3,
    unsigned char* __restrict__ hsP2, float* __restrict__ esE0,
    float* __restrict__ esE1, float* __restrict__ esP3,
    float* __restrict__ esP2, float* __restrict__ edEA,
    float* __restrict__ edEB, float* __restrict__ edPA,
    float* __restrict__ edPB) {
  gemm_body<false>(blockIdx.x, xe, xp, WbT, att, vec, l, hsE0, hsE1, hsP3,
                   hsP2, esE0, esE1, esP3, esP2, edEA, edEB, edPA, edPB);
}

// Layer-0 gemm (ids 0..586, long-running, launch first) + atomic-free CSR
// fill with CHUNK->XCD AFFINITY (all 13 blocks of chunk g share blockIdx%8).
// r10: bucketed 3-kernel fill (74us) lost to this direct scatter (54us,
// fabric partial-sector RMW floor) — accepted floor.
__global__ __launch_bounds__(512, 4) void fill_gemm0_k(
    const float* __restrict__ xe, const float* __restrict__ xp,
    const ushort* __restrict__ WbT, const float* __restrict__ att,
    const float* __restrict__ vec, unsigned char* __restrict__ hsE0,
    unsigned char* __restrict__ hsE1, unsigned char* __restrict__ hsP3,
    unsigned char* __restrict__ hsP2, float* __restrict__ esE0,
    float* __restrict__ esE1, float* __restrict__ esP3,
    float* __restrict__ esP2, float* __restrict__ edEA,
    float* __restrict__ edEB, float* __restrict__ edPA,
    float* __restrict__ edPB, const int* __restrict__ s0,
    const int* __restrict__ s1, const int* __restrict__ s2,
    const int* __restrict__ s3, const int* __restrict__ d0,
    const int* __restrict__ d1, const int* __restrict__ d2,
    const int* __restrict__ d3, const ushort* __restrict__ rk0,
    const ushort* __restrict__ rk1, const ushort* __restrict__ rk2,
    const ushort* __restrict__ rk3, const int* __restrict__ r0,
    const int* __restrict__ r1, const int* __restrict__ r2,
    const int* __restrict__ r3, const unsigned char* __restrict__ h0,
    const unsigned char* __restrict__ h1, const unsigned char* __restrict__ h2,
    const unsigned char* __restrict__ h3, ushort* __restrict__ o0,
    ushort* __restrict__ o1, ushort* __restrict__ o2,
    ushort* __restrict__ o3) {
  const int blk = blockIdx.x;
  if (blk < GEMM_BLK) {
    gemm_body<true>(blk, xe, xp, WbT, att, vec, 0, hsE0, hsE1, hsP3, hsP2,
                    esE0, esE1, esP3, esP2, edEA, edEB, edPA, edPB);
  } else {
    const int fb = blk - GEMM_BLK;
    const int x = fb & 7, q = fb >> 3;
    const int g = ((q & 15) << 3) | x;  // chunk 0..127; g%8 fixed per XCD
    const int j = q >> 4;               // 0..12 sub-block within chunk
    const int i = j * 512 + threadIdx.x;
    if (i >= CHK_E) return;
    const int ty = g >> 5, c = g & 31;
    const int e = c * CHK_E + i;
    const int NN = (ty == 0 || ty == 3) ? NE_N : NP_N;
    const int* src = ty == 0 ? s0 : ty == 1 ? s1 : ty == 2 ? s2 : s3;
    const int* dst = ty == 0 ? d0 : ty == 1 ? d1 : ty == 2 ? d2 : d3;
    const ushort* rk = ty == 0 ? rk0 : ty == 1 ? rk1 : ty == 2 ? rk2 : rk3;
    const int* rp = ty == 0 ? r0 : ty == 1 ? r1 : ty == 2 ? r2 : r3;
    const unsigned char* ho = ty == 0 ? h0 : ty == 1 ? h1 : ty == 2 ? h2 : h3;
    ushort* out = ty == 0 ? o0 : ty == 1 ? o1 : ty == 2 ? o2 : o3;
    const int dd = dst[e];
    out[rp[dd] + (int)ho[(size_t)c * NN + dd] + (int)rk[e]] =
        (ushort)src[e];
  }
}

// ---------------------------------------------------------------------------
// Combined dual-type gather, QUAD-NODE layout (r11) + DEGREE-SORTED perm
// (r14): node = perm[slot] so waves get 4 equal-degree nodes, collapsing
// the E[max of 8 Poisson streams] ~2x iteration quantization toward mean.
__global__ __launch_bounds__(256) void gat_gather_all(
    const int* __restrict__ rp0, const ushort* __restrict__ ss0,
    const int* __restrict__ rp1, const ushort* __restrict__ ss1,
    const int* __restrict__ rp2, const ushort* __restrict__ ss2,
    const int* __restrict__ rp3, const ushort* __restrict__ ss3,
    const float* __restrict__ esE0, const unsigned char* __restrict__ hsE0,
    const float* __restrict__ esE1, const unsigned char* __restrict__ hsE1,
    const float* __restrict__ esP3, const unsigned char* __restrict__ hsP3,
    const float* __restrict__ esP2, const unsigned char* __restrict__ hsP2,
    const float* __restrict__ edEA, const float* __restrict__ edEB,
    const float* __restrict__ edPA, const float* __restrict__ edPB,
    const float* __restrict__ bias, int l, ushort* __restrict__ outxe,
    ushort* __restrict__ outxp, int to_csum, float* __restrict__ csum_rep,
    const int* __restrict__ permE, const int* __restrict__ permP) {
  const int lane = threadIdx.x & 63;
  const int wv = threadIdx.x >> 6;
  const int half = (lane >> 3) & 1;
  const int sub = lane & 7;
  const int wid = (blockIdx.x * 256 + threadIdx.x) >> 4;  // global node slot
  const bool active = wid < NE_N + NP_N;

  const float *b0 = bias, *b1 = bias;
  ushort* outb = outxe;
  int node = 0;
  int beg = 0, end = 0;
  const ushort* ss = ss0;
  const float* es = esE0;
  const unsigned char* hs = hsE0;
  float edv = 0.f;

  if (active) {
    if (wid < NE_N) {  // e-dst: ee (half 0) + pe (half 1)
      node = permE[wid];
      if (half == 0) { ss = ss0; es = esE0; hs = hsE0; edv = edEA[node];
                       beg = rp0[node]; end = rp0[node + 1]; }
      else           { ss = ss3; es = esP3; hs = hsP3; edv = edEB[node];
                       beg = rp3[node]; end = rp3[node + 1]; }
      b0 = bias + (l * 4 + 0) * DIM; b1 = bias + (l * 4 + 3) * DIM;
      outb = outxe;
    } else {  // p-dst: ep (half 0) + pp (half 1)
      node = permP[wid - NE_N];
      if (half == 0) { ss = ss1; es = esE1; hs = hsE1; edv = edPA[node];
                       beg = rp1[node]; end = rp1[node + 1]; }
      else           { ss = ss2; es = esP2; hs = hsP2; edv = edPB[node];
                       beg = rp2[node]; end = rp2[node + 1]; }
      b0 = bias + (l * 4 + 1) * DIM; b1 = bias + (l * 4 + 2) * DIM;
      outb = outxp;
    }
  }

  f32x2 acc2[8];
#pragma unroll
  for (int j = 0; j < 8; j++) acc2[j] = (f32x2){0.f, 0.f};
  float sw = 0.f;

  // one-deep pipelined gather loop
  float esC = 0.f;
  uint4 hC = make_uint4(0, 0, 0, 0);
  if (beg < end) {
    const int s0v = ss[beg];
    esC = es[s0v];
    hC = *(const uint4*)&hs[(size_t)s0v * DIM + sub * 16];
  }
  for (int e = beg; e < end; e++) {
    const int en = (e + 1 < end) ? e + 1 : e;
    const int sn = ss[en];
    const float esN = es[sn];
    const uint4 hN = *(const uint4*)&hs[(size_t)sn * DIM + sub * 16];

    const float w = exp2f(fmaxf(esC + edv, 0.f));
    sw += w;
    const f32x2 w2 = {w, w};
    acc2[0] += w2 * __builtin_amdgcn_cvt_pk_f32_fp8((int)hC.x, false);
    acc2[1] += w2 * __builtin_amdgcn_cvt_pk_f32_fp8((int)hC.x, true);
    acc2[2] += w2 * __builtin_amdgcn_cvt_pk_f32_fp8((int)hC.y, false);
    acc2[3] += w2 * __builtin_amdgcn_cvt_pk_f32_fp8((int)hC.y, true);
    acc2[4] += w2 * __builtin_amdgcn_cvt_pk_f32_fp8((int)hC.z, false);
    acc2[5] += w2 * __builtin_amdgcn_cvt_pk_f32_fp8((int)hC.z, true);
    acc2[6] += w2 * __builtin_amdgcn_cvt_pk_f32_fp8((int)hC.w, false);
    acc2[7] += w2 * __builtin_amdgcn_cvt_pk_f32_fp8((int)hC.w, true);
    esC = esN;
    hC = hN;
  }

  // sw is lane-local (single stream); normalize, then cross-half combine
  const float inv = 1.f / fmaxf(sw, 1e-16f);
#pragma unroll
  for (int j = 0; j < 8; j++) {
    acc2[j].x *= inv;
    acc2[j].y *= inv;
    f32x2 t;
    t.x = __shfl_xor(acc2[j].x, 8, 64);
    t.y = __shfl_xor(acc2[j].y, 8, 64);
    acc2[j] += t;
  }

  if (to_csum) {
    // cross-quad combine: every lane ends with the 4-node sum for its cols
#pragma unroll
    for (int j = 0; j < 8; j++) {
      f32x2 t;
      t.x = __shfl_xor(acc2[j].x, 16, 64);
      t.y = __shfl_xor(acc2[j].y, 16, 64);
      acc2[j] += t;
      t.x = __shfl_xor(acc2[j].x, 32, 64);
      t.y = __shfl_xor(acc2[j].y, 32, 64);
      acc2[j] += t;
    }
    __shared__ float lsum[4][DIM];
    if (lane < 8) {  // quad 0, half 0: covers all 128 cols across 8 subs
#pragma unroll
      for (int j = 0; j < 8; j++)
        *(float2*)&lsum[wv][sub * 16 + 2 * j] =
            make_float2(acc2[j].x, acc2[j].y);
    }
    __syncthreads();
    if (threadIdx.x < DIM) {
      float s = lsum[0][threadIdx.x] + lsum[1][threadIdx.x] +
                lsum[2][threadIdx.x] + lsum[3][threadIdx.x];
      float* rep = csum_rep + (size_t)(blockIdx.x & (NREP - 1)) * DIM;
      unsafeAtomicAdd(&rep[threadIdx.x], s);
    }
  } else if (active && half == 0) {
    // lane owns cols [sub*16, sub*16+16): assemble 32B (2x uint4) row slice
    unsigned ow[8];
#pragma unroll
    for (int j = 0; j < 8; j++) {
      const int d = sub * 16 + 2 * j;
      float2 bb0 = *(const float2*)&b0[d];
      float2 bb1 = *(const float2*)&b1[d];
      unsigned lo = f2bf(acc2[j].x + bb0.x + bb1.x);
      unsigned hi = f2bf(acc2[j].y + bb0.y + bb1.y);
      ow[j] = lo | (hi << 16);
    }
    uint4* op = (uint4*)&outb[(size_t)node * DIM + sub * 16];
    op[0] = make_uint4(ow[0], ow[1], ow[2], ow[3]);
    op[1] = make_uint4(ow[4], ow[5], ow[6], ow[7]);
  }
}

// ---------------------------------------------------------------------------
// final: reduce NREP csum replicas, add analytic bias term, project.
__global__ __launch_bounds__(512) void final_proj(
    const float* __restrict__ csum_rep, const float* __restrict__ bias,
    const float* __restrict__ lin_W, const float* __restrict__ lin_b,
    float* __restrict__ out) {
  __shared__ float parts[4][DIM];
  __shared__ float col[DIM];
  const int k = threadIdx.x & 127;   // column
  const int pt = threadIdx.x >> 7;   // replica partition 0..3
  float s = 0.f;
#pragma unroll 8
  for (int r = pt * (NREP / 4); r < (pt + 1) * (NREP / 4); r++)
    s += csum_rep[(size_t)r * DIM + k];
  parts[pt][k] = s;
  __syncthreads();
  if (threadIdx.x < DIM) {
    const float* bE0 = bias + (2 * 4 + 0) * DIM;
    const float* bE1 = bias + (2 * 4 + 3) * DIM;
    const float* bP0 = bias + (2 * 4 + 1) * DIM;
    const float* bP1 = bias + (2 * 4 + 2) * DIM;
    col[k] = parts[0][k] + parts[1][k] + parts[2][k] + parts[3][k] +
             (float)NE_N * (bE0[k] + bE1[k]) +
             (float)NP_N * (bP0[k] + bP1[k]);
  }
  __syncthreads();
  if (threadIdx.x < 2) {
    float acc = 0.f;
#pragma unroll 8
    for (int j = 0; j < DIM; j++) acc += col[j] * lin_W[j * 2 + threadIdx.x];
    out[threadIdx.x] = acc / (float)(NE_N + NP_N) + lin_b[threadIdx.x];
  }
}

// ---------------------------------------------------------------------------
extern "C" void kernel_launch(void* const* d_in, const int* in_sizes, int n_in,
                              void* d_out, int out_size, void* d_ws,
                              size_t ws_size, hipStream_t stream) {
  const float* x_elem  = (const float*)d_in[0];
  const float* x_proc  = (const float*)d_in[1];
  const float* W_src   = (const float*)d_in[2];
  const float* W_dst   = (const float*)d_in[3];
  const float* att_src = (const float*)d_in[4];
  const float* att_dst = (const float*)d_in[5];
  const float* bias    = (const float*)d_in[6];
  const float* lin_W   = (const float*)d_in[7];
  const float* lin_b   = (const float*)d_in[8];
  const int* esrc[4] = {(const int*)d_in[9],  (const int*)d_in[11],
                        (const int*)d_in[13], (const int*)d_in[15]};
  const int* edst[4] = {(const int*)d_in[10], (const int*)d_in[12],
                        (const int*)d_in[14], (const int*)d_in[16]};

  // ---- workspace carve-up (16B-aligned chunks) ----
  char* p = (char*)d_ws;
  ushort* xe_bf[2]; ushort* xp_bf[2];
  xe_bf[0] = (ushort*)p; p += (size_t)NE_N * DIM * 2;
  xe_bf[1] = (ushort*)p; p += (size_t)NE_N * DIM * 2;
  xp_bf[0] = (ushort*)p; p += (size_t)NP_N * DIM * 2;
  xp_bf[1] = (ushort*)p; p += (size_t)NP_N * DIM * 2;
  unsigned char* hsE0 = (unsigned char*)p; p += (size_t)NE_N * DIM;  // W[l,0]
  unsigned char* hsE1 = (unsigned char*)p; p += (size_t)NE_N * DIM;  // W[l,1]
  unsigned char* hsP3 = (unsigned char*)p; p += (size_t)NP_N * DIM;  // W[l,3]
  unsigned char* hsP2 = (unsigned char*)p; p += (size_t)NP_N * DIM;  // W[l,2]
  ushort* WbT = (ushort*)p; p += (size_t)12 * DIM * DIM * 2;
  float* esE0 = (float*)p; p += (size_t)NE_N * 4;
  float* esE1 = (float*)p; p += (size_t)NE_N * 4;
  float* esP3 = (float*)p; p += (size_t)NP_N * 4;
  float* esP2 = (float*)p; p += (size_t)NP_N * 4;
  float* edEA = (float*)p; p += (size_t)NE_N * 4;
  float* edEB = (float*)p; p += (size_t)NE_N * 4;
  float* edPA = (float*)p; p += (size_t)NP_N * 4;
  float* edPB = (float*)p; p += (size_t)NP_N * 4;
  float* vec = (float*)p; p += 12 * DIM * 4;
  int* parti = (int*)p; p += 4 * 64 * 4;
  // csum_rep + chunk-hist arrays contiguous -> single memset
  float* csum_rep = (float*)p; p += (size_t)NREP * DIM * 4;
  unsigned char* hh[4];
  hh[0] = (unsigned char*)p; p += (size_t)NE_N * NCHK;
  hh[1] = (unsigned char*)p; p += (size_t)NP_N * NCHK;
  hh[2] = (unsigned char*)p; p += (size_t)NP_N * NCHK;
  hh[3] = (unsigned char*)p; p += (size_t)NE_N * NCHK;
  int* cnt[4];
  for (int t = 0; t < 4; t++) { cnt[t] = (int*)p; p += (NE_N + 4) * 4; }
  int* rp[4];
  for (int t = 0; t < 4; t++) { rp[t] = (int*)p; p += (NE_N + 4) * 4; }
  ushort* ssrc[4];
  for (int t = 0; t < 4; t++) { ssrc[t] = (ushort*)p; p += (size_t)E_N * 2; }
  ushort* rank[4];
  for (int t = 0; t < 4; t++) { rank[t] = (ushort*)p; p += (size_t)E_N * 2; }
  int* permE = (int*)p; p += (size_t)NE_N * 4;
  int* permP = (int*)p; p += (size_t)NP_N * 4;
  unsigned* bh = (unsigned*)p; p += (size_t)2 * NBIN * EB49 * 4;
  unsigned* boff = (unsigned*)p; p += (size_t)2 * NBIN * EB49 * 4;

  // ---- zero csum replicas + chunk hists in one memset ----
  hipMemsetAsync(csum_rep, 0,
                 (size_t)NREP * DIM * 4 +
                     (size_t)(2 * NE_N + 2 * NP_N) * NCHK,
                 stream);

  // ---- fused: LDS-hash rank build | conv_w | vec (no device atomics) ----
  hist_setup_k<<<HS_TOT, 512, 0, stream>>>(
      W_src, W_dst, att_dst, WbT, vec, edst[0], edst[1], edst[2], edst[3],
      hh[0], hh[1], hh[2], hh[3], rank[0], rank[1], rank[2], rank[3]);

  // ---- scan: chunk-offset prefix + cnt (A), rp writeback (BC) ----
  scanA_k<<<dim3(49, 4), 256, 0, stream>>>(hh[0], hh[1], hh[2], hh[3],
                                           cnt[0], cnt[1], cnt[2], cnt[3],
                                           parti);
  scanBC_k<<<dim3(49, 4), 256, 0, stream>>>(cnt[0], cnt[1], cnt[2], cnt[3],
                                            rp[0], rp[1], rp[2], rp[3], parti);

  // ---- degree-sort perm (counting, 3 small dispatches) ----
  sortA_k<<<dim3(EB49, 2), 256, 0, stream>>>(rp[0], rp[3], rp[1], rp[2], bh);
  sortB_k<<<1, 256, 0, stream>>>(bh, boff);
  sortC_k<<<dim3(EB49, 2), 256, 0, stream>>>(rp[0], rp[3], rp[1], rp[2],
                                             boff, permE, permP);

  // ---- layer-0 gemm (first, long-running) + XCD-affine atomic-free fill ----
  fill_gemm0_k<<<HG2_TOT, 512, 0, stream>>>(
      x_elem, x_proc, WbT, att_src, vec, hsE0, hsE1, hsP3, hsP2, esE0, esE1,
      esP3, esP2, edEA, edEB, edPA, edPB, esrc[0], esrc[1], esrc[2], esrc[3],
      edst[0], edst[1], edst[2], edst[3], rank[0], rank[1], rank[2], rank[3],
      rp[0], rp[1], rp[2], rp[3], hh[0], hh[1], hh[2], hh[3],
      ssrc[0], ssrc[1], ssrc[2], ssrc[3]);

  // ---- layers ----
  int c = 0;
  for (int l = 0; l < 3; l++) {
    if (l > 0) {
      gemm_k<<<GEMM_BLK, 512, 0, stream>>>(
          xe_bf[c], xp_bf[c], WbT, att_src, vec, l, hsE0, hsE1, hsP3, hsP2,
          esE0, esE1, esP3, esP2, edEA, edEB, edPA, edPB);
    }
    int to_csum = (l == 2) ? 1 : 0;
    gat_gather_all<<<(NE_N + NP_N + 15) / 16, 256, 0, stream>>>(
        rp[0], ssrc[0], rp[1], ssrc[1], rp[2], ssrc[2], rp[3], ssrc[3], esE0,
        hsE0, esE1, hsE1, esP3, hsP3, esP2, hsP2, edEA, edEB, edPA, edPB,
        bias, l, xe_bf[1 - c], xp_bf[1 - c], to_csum, csum_rep, permE, permP);
    c = 1 - c;
  }

  final_proj<<<1, 512, 0, stream>>>(csum_rep, bias, lin_W, lin_b,
                                    (float*)d_out);
}

// Round 15
// 353.780 us; speedup vs baseline: 1.0605x; 1.0605x over previous
//
#include <hip/hip_runtime.h>

#define NE_N 50000
#define NP_N 25000
#define E_N 200000
#define DIM 128
#define LOG2E 1.4426950408889634f
#define NREP 1024  // csum replicas

// rank build: 32 chunks/type, LDS hash per chunk -> zero device atomics
#define NCHK 32
#define CHK_E (E_N / NCHK)  // 6250
#define TBL 16384           // hash slots; load factor 6250/16384 = 0.38

typedef __attribute__((ext_vector_type(8))) short short8;
typedef __attribute__((ext_vector_type(4))) float f32x4;
typedef __attribute__((ext_vector_type(2))) float f32x2;

static __device__ __forceinline__ ushort f2bf(float f) {
  unsigned x = __float_as_uint(f);
  return (ushort)((x + 0x7fffu + ((x >> 16) & 1u)) >> 16);  // RNE
}
static __device__ __forceinline__ float bf2f(ushort u) {
  return __uint_as_float(((unsigned)u) << 16);
}

// async global->LDS, 16B/lane; LDS dest is WAVE-UNIFORM base + lane*16.
static __device__ __forceinline__ void gload_lds16(const void* g, void* l) {
  __builtin_amdgcn_global_load_lds(
      (const __attribute__((address_space(1))) void*)g,
      (__attribute__((address_space(3))) void*)l, 16, 0, 0);
}

// ---------------------------------------------------------------------------
// Fused: per-chunk LDS-hash rank build (128 blk) | conv_w (12) | vec (3).
// hh is CHUNK-MAJOR uchar h[c*N + node] (counts <= max degree ~30 << 255).
#define HIST_BLKS (4 * NCHK)            // 128
#define HS_TOT (HIST_BLKS + 12 + 3)     // +conv_w +vec
__global__ __launch_bounds__(512) void hist_setup_k(
    const float* __restrict__ W_src, const float* __restrict__ W_dst,
    const float* __restrict__ att_dst, ushort* __restrict__ WbT,
    float* __restrict__ vec, const int* __restrict__ d0,
    const int* __restrict__ d1, const int* __restrict__ d2,
    const int* __restrict__ d3, unsigned char* __restrict__ h0,
    unsigned char* __restrict__ h1, unsigned char* __restrict__ h2,
    unsigned char* __restrict__ h3, ushort* __restrict__ rk0,
    ushort* __restrict__ rk1, ushort* __restrict__ rk2,
    ushort* __restrict__ rk3) {
  __shared__ int keys[TBL];
  __shared__ int cnts[TBL];
  const int blk = blockIdx.x;
  const int tid = threadIdx.x;
  if (blk < HIST_BLKS) {
    const int ty = blk >> 5, c = blk & (NCHK - 1);
    const int NN = (ty == 0 || ty == 3) ? NE_N : NP_N;
    const int* dst = ty == 0 ? d0 : ty == 1 ? d1 : ty == 2 ? d2 : d3;
    unsigned char* h = ty == 0 ? h0 : ty == 1 ? h1 : ty == 2 ? h2 : h3;
    ushort* rk = ty == 0 ? rk0 : ty == 1 ? rk1 : ty == 2 ? rk2 : rk3;
    for (int i = tid; i < TBL; i += 512) { keys[i] = -1; cnts[i] = 0; }
    __syncthreads();
    const int base = c * CHK_E;
    for (int i = tid; i < CHK_E; i += 512) {
      const int e = base + i;
      const int d = dst[e];
      unsigned hsh = ((unsigned)d * 2654435761u) >> 18;
      hsh &= (TBL - 1);
      int lr;
      while (true) {
        int prev = atomicCAS(&keys[hsh], -1, d);
        if (prev == -1 || prev == d) { lr = atomicAdd(&cnts[hsh], 1); break; }
        hsh = (hsh + 1) & (TBL - 1);
      }
      rk[e] = (ushort)lr;
    }
    __syncthreads();
    for (int i = tid; i < TBL; i += 512) {
      int k = keys[i];
      if (k >= 0) h[(size_t)c * NN + k] = (unsigned char)cnts[i];
    }
  } else if (blk < HIST_BLKS + 12) {
    const int w = blk - HIST_BLKS;
    const float* src = W_src + (size_t)w * DIM * DIM;
    ushort* dstw = WbT + (size_t)w * DIM * DIM;
    for (int i = tid; i < DIM * DIM; i += 512) {
      int k = i >> 7, n = i & 127;
      dstw[n * DIM + k] = f2bf(src[i]);
    }
  } else {
    const int b = blk - HIST_BLKS - 12;
    const int lt = b * 4 + (tid >> 7);
    const int i = tid & 127;
    const float* Wd = W_dst + (size_t)lt * DIM * DIM;
    const float* ad = att_dst + lt * DIM;
    float s = 0.f;
#pragma unroll 8
    for (int j = 0; j < DIM; j++) s += Wd[i * DIM + j] * ad[j];
    vec[lt * DIM + i] = s;
  }
}

// ---------------------------------------------------------------------------
// CSR scan. scanA: chunk-major uchar h -> 32 coalesced 4B passes per node
// group; in-place exclusive prefix over chunks; emit cnt=degree + block sums.
__global__ __launch_bounds__(256) void scanA_k(
    unsigned char* __restrict__ h0, unsigned char* __restrict__ h1,
    unsigned char* __restrict__ h2, unsigned char* __restrict__ h3,
    int* __restrict__ c0, int* __restrict__ c1, int* __restrict__ c2,
    int* __restrict__ c3, int* __restrict__ part) {
  int ty = blockIdx.y;
  unsigned char* h = ty == 0 ? h0 : ty == 1 ? h1 : ty == 2 ? h2 : h3;
  int* cnt = ty == 0 ? c0 : ty == 1 ? c1 : ty == 2 ? c2 : c3;
  int n = (ty == 0 || ty == 3) ? NE_N : NP_N;  // both divisible by 4
  int nblk = (n + 1023) >> 10;
  if ((int)blockIdx.x >= nblk) return;
  int base = blockIdx.x * 1024 + threadIdx.x * 4;
  int s = 0;
  if (base < n) {
    int run0 = 0, run1 = 0, run2 = 0, run3 = 0;
#pragma unroll
    for (int c = 0; c < NCHK; c++) {
      unsigned* hp = (unsigned*)(h + (size_t)c * n + base);
      unsigned v = *hp;
      *hp = (unsigned)(run0 & 255) | ((unsigned)(run1 & 255) << 8) |
            ((unsigned)(run2 & 255) << 16) | ((unsigned)(run3 & 255) << 24);
      run0 += (int)(v & 255u);
      run1 += (int)((v >> 8) & 255u);
      run2 += (int)((v >> 16) & 255u);
      run3 += (int)((v >> 24) & 255u);
    }
    cnt[base + 0] = run0; cnt[base + 1] = run1;
    cnt[base + 2] = run2; cnt[base + 3] = run3;
    s = run0 + run1 + run2 + run3;
  }
  int lane = threadIdx.x & 63, wid = threadIdx.x >> 6;
#pragma unroll
  for (int off = 32; off > 0; off >>= 1) s += __shfl_xor(s, off, 64);
  __shared__ int ws4[4];
  if (lane == 0) ws4[wid] = s;
  __syncthreads();
  if (threadIdx.x == 0)
    part[ty * 64 + blockIdx.x] = ws4[0] + ws4[1] + ws4[2] + ws4[3];
}

__global__ __launch_bounds__(256) void scanBC_k(
    const int* __restrict__ c0, const int* __restrict__ c1,
    const int* __restrict__ c2, const int* __restrict__ c3,
    int* __restrict__ r0, int* __restrict__ r1, int* __restrict__ r2,
    int* __restrict__ r3, const int* __restrict__ part) {
  int ty = blockIdx.y;
  int bx = blockIdx.x;
  const int* cnt = ty == 0 ? c0 : ty == 1 ? c1 : ty == 2 ? c2 : c3;
  int* rp = ty == 0 ? r0 : ty == 1 ? r1 : ty == 2 ? r2 : r3;
  int n = (ty == 0 || ty == 3) ? NE_N : NP_N;
  int nblk = (n + 1023) >> 10;
  if (bx >= nblk) return;

  __shared__ int s_excl;
  if (threadIdx.x < 64) {
    int pl = threadIdx.x;
    int v = (pl < nblk) ? part[ty * 64 + pl] : 0;
    int sc = v;
#pragma unroll
    for (int off = 1; off < 64; off <<= 1) {
      int t = __shfl_up(sc, off, 64);
      if (pl >= off) sc += t;
    }
    if (pl == bx) s_excl = sc - v;
  }
  if (bx == 0 && threadIdx.x == 0) rp[n] = E_N;  // total is always E_N
  __syncthreads();

  int base = bx * 1024 + threadIdx.x * 4;
  int v[4];
#pragma unroll
  for (int j = 0; j < 4; j++) v[j] = (base + j < n) ? cnt[base + j] : 0;
  int s = v[0] + v[1] + v[2] + v[3];
  int lane = threadIdx.x & 63, wid = threadIdx.x >> 6;
  int sc = s;
#pragma unroll
  for (int off = 1; off < 64; off <<= 1) {
    int t = __shfl_up(sc, off, 64);
    if (lane >= off) sc += t;
  }
  __shared__ int ws4[4];
  if (lane == 63) ws4[wid] = sc;
  __syncthreads();
  int wbase = 0;
  for (int w = 0; w < wid; w++) wbase += ws4[w];
  int p = s_excl + wbase + sc - s;
#pragma unroll
  for (int j = 0; j < 4; j++) {
    if (base + j < n) rp[base + j] = p;
    p += v[j];
  }
}

// ---------------------------------------------------------------------------
// GEMM: 8-wave (512-thr) blocks, 128 rows/block, W staged via global_load_lds.
// 128-row blocks (587) fill the 2-per-CU LDS slots in ~1.15 rounds; r7's
// 256-row (294 blocks) left 85% of CUs idle through a 2x straggler tail.
#define EBLK ((NE_N + 127) / 128)     // 391
#define PBLK ((NP_N + 127) / 128)     // 196
#define GEMM_BLK (EBLK + PBLK)        // 587
#define FILL_PER_CHK 13               // ceil(6250/512)
#define FILL_BLKS (4 * NCHK * FILL_PER_CHK)  // 1664
#define HG2_TOT (GEMM_BLK + FILL_BLKS)       // 2251

template <bool FP32>
static __device__ __forceinline__ void x_prefetch(
    const void* xb, int rowA, int quad, float4* xraw, short8* xvv) {
  if (FP32) {
    const float* xf32 = (const float*)xb + (size_t)rowA * DIM + quad * 8;
#pragma unroll
    for (int k0 = 0; k0 < 4; k0++) {
      xraw[2 * k0] = *(const float4*)(xf32 + k0 * 32);
      xraw[2 * k0 + 1] = *(const float4*)(xf32 + k0 * 32 + 4);
    }
  } else {
    const ushort* xb16 = (const ushort*)xb + (size_t)rowA * DIM + quad * 8;
#pragma unroll
    for (int k0 = 0; k0 < 4; k0++)
      xvv[k0] = *(const short8*)(xb16 + k0 * 32);
  }
}

template <bool FP32>
static __device__ __forceinline__ void strip_body(
    int row0, int N, int m, int quad, int lane, const short8* wlds,
    const float* dv0, const float* dv1, const float* a0, const float* a1,
    unsigned char* hs0, unsigned char* hs1, float* es0, float* es1,
    float* edA, float* edB, float4* xraw, short8* xvv) {
  // ---- ed partials + bf16 pack ----
  float edp0 = 0.f, edp1 = 0.f;
#pragma unroll
  for (int k0 = 0; k0 < 4; k0++) {
    float xf[8];
    if (FP32) {
      float4 f0 = xraw[2 * k0], f1 = xraw[2 * k0 + 1];
      xf[0] = f0.x; xf[1] = f0.y; xf[2] = f0.z; xf[3] = f0.w;
      xf[4] = f1.x; xf[5] = f1.y; xf[6] = f1.z; xf[7] = f1.w;
      short8 xv;
#pragma unroll
      for (int j = 0; j < 8; j++) xv[j] = (short)f2bf(xf[j]);
      xvv[k0] = xv;
    } else {
#pragma unroll
      for (int j = 0; j < 8; j++) xf[j] = bf2f((ushort)xvv[k0][j]);
    }
    int off = k0 * 32 + quad * 8;
    float4 vA0 = *(const float4*)&dv0[off];
    float4 vA1 = *(const float4*)&dv0[off + 4];
    float4 vB0 = *(const float4*)&dv1[off];
    float4 vB1 = *(const float4*)&dv1[off + 4];
    edp0 += xf[0] * vA0.x + xf[1] * vA0.y + xf[2] * vA0.z + xf[3] * vA0.w +
            xf[4] * vA1.x + xf[5] * vA1.y + xf[6] * vA1.z + xf[7] * vA1.w;
    edp1 += xf[0] * vB0.x + xf[1] * vB0.y + xf[2] * vB0.z + xf[3] * vB0.w +
            xf[4] * vB1.x + xf[5] * vB1.y + xf[6] * vB1.z + xf[7] * vB1.w;
  }

  // ---- MFMA (LDS fragments, conflict-free linear) ----
  f32x4 acc0[8], acc1[8];
#pragma unroll
  for (int f = 0; f < 8; f++) {
    acc0[f] = (f32x4){0.f, 0.f, 0.f, 0.f};
    acc1[f] = (f32x4){0.f, 0.f, 0.f, 0.f};
  }
#pragma unroll
  for (int k0 = 0; k0 < 4; k0++) {
    const short8 xv = xvv[k0];
#pragma unroll
    for (int f = 0; f < 8; f++) {
      acc0[f] = __builtin_amdgcn_mfma_f32_16x16x32_bf16(
          wlds[(k0 * 8 + f) * 64 + lane], xv, acc0[f], 0, 0, 0);
      acc1[f] = __builtin_amdgcn_mfma_f32_16x16x32_bf16(
          wlds[2048 + (k0 * 8 + f) * 64 + lane], xv, acc1[f], 0, 0, 0);
    }
  }

  const int row = row0 + m;
  edp0 += __shfl_xor(edp0, 16, 64);
  edp0 += __shfl_xor(edp0, 32, 64);
  edp1 += __shfl_xor(edp1, 16, 64);
  edp1 += __shfl_xor(edp1, 32, 64);
  if (quad == 0 && row < N) {
    edA[row] = edp0 * LOG2E;
    edB[row] = edp1 * LOG2E;
  }

#pragma unroll
  for (int set = 0; set < 2; set++) {
    f32x4* acc = set ? acc1 : acc0;
    const float* as = set ? a1 : a0;
    float* es = set ? es1 : es0;
    unsigned char* hs = set ? hs1 : hs0;

    float esum = 0.f;
#pragma unroll
    for (int f = 0; f < 8; f++) {
      float4 av = *(const float4*)&as[f * 16 + quad * 4];
      esum += acc[f][0] * av.x + acc[f][1] * av.y + acc[f][2] * av.z +
              acc[f][3] * av.w;
    }
    esum += __shfl_xor(esum, 16, 64);
    esum += __shfl_xor(esum, 32, 64);
    if (quad == 0 && row < N) es[row] = esum * LOG2E;

    if (row < N) {
#pragma unroll
      for (int f = 0; f < 8; f++) {
        int w = __builtin_amdgcn_cvt_pk_fp8_f32(acc[f][0], acc[f][1], 0, false);
        w = __builtin_amdgcn_cvt_pk_fp8_f32(acc[f][2], acc[f][3], w, true);
        *(unsigned*)&hs[(size_t)row * DIM + f * 16 + quad * 4] = (unsigned)w;
      }
    }
  }
}

template <bool FP32>
static __device__ __forceinline__ void gemm_body(
    int blk, const void* __restrict__ xev, const void* __restrict__ xpv,
    const ushort* __restrict__ WbT, const float* __restrict__ att,
    const float* __restrict__ vec, int l, unsigned char* __restrict__ hsE0,
    unsigned char* __restrict__ hsE1, unsigned char* __restrict__ hsP3,
    unsigned char* __restrict__ hsP2, float* __restrict__ esE0,
    float* __restrict__ esE1, float* __restrict__ esP3,
    float* __restrict__ esP2, float* __restrict__ edEA,
    float* __restrict__ edEB, float* __restrict__ edPA,
    float* __restrict__ edPB) {
  const void* xb;
  const ushort *W0T, *W1T;
  const float *a0, *a1, *dv0, *dv1;
  unsigned char *hs0, *hs1;
  float *es0, *es1, *edA, *edB;
  int N, rbase;
  if (blk < EBLK) {
    xb = xev; N = NE_N; rbase = blk * 128;
    W0T = WbT + (size_t)(l * 4 + 0) * DIM * DIM;
    W1T = WbT + (size_t)(l * 4 + 1) * DIM * DIM;
    a0 = att + (l * 4 + 0) * DIM; a1 = att + (l * 4 + 1) * DIM;
    dv0 = vec + (l * 4 + 0) * DIM; dv1 = vec + (l * 4 + 3) * DIM;
    hs0 = hsE0; hs1 = hsE1; es0 = esE0; es1 = esE1;
    edA = edEA; edB = edEB;
  } else {
    blk -= EBLK; xb = xpv; N = NP_N; rbase = blk * 128;
    W0T = WbT + (size_t)(l * 4 + 3) * DIM * DIM;
    W1T = WbT + (size_t)(l * 4 + 2) * DIM * DIM;
    a0 = att + (l * 4 + 3) * DIM; a1 = att + (l * 4 + 2) * DIM;
    dv0 = vec + (l * 4 + 1) * DIM; dv1 = vec + (l * 4 + 2) * DIM;
    hs0 = hsP3; hs1 = hsP2; es0 = esP3; es1 = esP2;
    edA = edPA; edB = edPB;
  }

  const int wave = threadIdx.x >> 6;
  const int lane = threadIdx.x & 63;
  const int m = lane & 15, quad = lane >> 4;
  const int row0 = rbase + wave * 16;
  int rowL = row0 + m;
  if (rowL >= N) rowL = N - 1;  // clamp loads; stores guarded

  // ---- x prefetch (hides under W staging) ----
  float4 xraw[8]; short8 xvv[4];
  x_prefetch<FP32>(xb, rowL, quad, xraw, xvv);

  // ---- stage W0T,W1T into LDS via global_load_lds (uniform base+lane*16) --
  __shared__ short8 wlds[4096];  // 64KB: 2 sets x 4 k0 x 8 f x 64 lanes x 16B
  {
    const int i15 = lane & 15, i4 = lane >> 4;
#pragma unroll
    for (int r = 0; r < 8; r++) {
      const int g = r * 8 + wave;           // 0..63, each exactly once
      const int set = g >> 5, k0 = (g >> 3) & 3, f = g & 7;
      const ushort* WT = set ? W1T : W0T;
      gload_lds16(WT + (size_t)(f * 16 + i15) * DIM + k0 * 32 + i4 * 8,
                  &wlds[g * 64]);
    }
  }
  __syncthreads();
  if (row0 >= N) return;  // tail waves: staged + synced, no compute

  strip_body<FP32>(row0, N, m, quad, lane, wlds, dv0, dv1, a0, a1,
                   hs0, hs1, es0, es1, edA, edB, xraw, xvv);
}

// standalone gemm (layers 1,2 — bf16 input)
__global__ __launch_bounds__(512, 4) void gemm_k(
    const ushort* __restrict__ xe, const ushort* __restrict__ xp,
    const ushort* __restrict__ WbT, const float* __restrict__ att,
    const float* __restrict__ vec, int l, unsigned char* __restrict__ hsE0,
    unsigned char* __restrict__ hsE1, unsigned char* __restrict__ hsP3,
    unsigned char* __restrict__ hsP2, float* __restrict__ esE0,
    float* __restrict__ esE1, float* __restrict__ esP3,
    float* __restrict__ esP2, float* __restrict__ edEA,
    float* __restrict__ edEB, float* __restrict__ edPA,
    float* __restrict__ edPB) {
  gemm_body<false>(blockIdx.x, xe, xp, WbT, att, vec, l, hsE0, hsE1, hsP3,
                   hsP2, esE0, esE1, esP3, esP2, edEA, edEB, edPA, edPB);
}

// Layer-0 gemm (ids 0..586, long-running, launch first) + atomic-free CSR
// fill with CHUNK->XCD AFFINITY (all 13 blocks of chunk g share blockIdx%8).
// r10: bucketed 3-kernel fill (74us) lost to this direct scatter (54us,
// fabric partial-sector RMW floor) — accepted floor.
__global__ __launch_bounds__(512, 4) void fill_gemm0_k(
    const float* __restrict__ xe, const float* __restrict__ xp,
    const ushort* __restrict__ WbT, const float* __restrict__ att,
    const float* __restrict__ vec, unsigned char* __restrict__ hsE0,
    unsigned char* __restrict__ hsE1, unsigned char* __restrict__ hsP3,
    unsigned char* __restrict__ hsP2, float* __restrict__ esE0,
    float* __restrict__ esE1, float* __restrict__ esP3,
    float* __restrict__ esP2, float* __restrict__ edEA,
    float* __restrict__ edEB, float* __restrict__ edPA,
    float* __restrict__ edPB, const int* __restrict__ s0,
    const int* __restrict__ s1, const int* __restrict__ s2,
    const int* __restrict__ s3, const int* __restrict__ d0,
    const int* __restrict__ d1, const int* __restrict__ d2,
    const int* __restrict__ d3, const ushort* __restrict__ rk0,
    const ushort* __restrict__ rk1, const ushort* __restrict__ rk2,
    const ushort* __restrict__ rk3, const int* __restrict__ r0,
    const int* __restrict__ r1, const int* __restrict__ r2,
    const int* __restrict__ r3, const unsigned char* __restrict__ h0,
    const unsigned char* __restrict__ h1, const unsigned char* __restrict__ h2,
    const unsigned char* __restrict__ h3, ushort* __restrict__ o0,
    ushort* __restrict__ o1, ushort* __restrict__ o2,
    ushort* __restrict__ o3) {
  const int blk = blockIdx.x;
  if (blk < GEMM_BLK) {
    gemm_body<true>(blk, xe, xp, WbT, att, vec, 0, hsE0, hsE1, hsP3, hsP2,
                    esE0, esE1, esP3, esP2, edEA, edEB, edPA, edPB);
  } else {
    const int fb = blk - GEMM_BLK;
    const int x = fb & 7, q = fb >> 3;
    const int g = ((q & 15) << 3) | x;  // chunk 0..127; g%8 fixed per XCD
    const int j = q >> 4;               // 0..12 sub-block within chunk
    const int i = j * 512 + threadIdx.x;
    if (i >= CHK_E) return;
    const int ty = g >> 5, c = g & 31;
    const int e = c * CHK_E + i;
    const int NN = (ty == 0 || ty == 3) ? NE_N : NP_N;
    const int* src = ty == 0 ? s0 : ty == 1 ? s1 : ty == 2 ? s2 : s3;
    const int* dst = ty == 0 ? d0 : ty == 1 ? d1 : ty == 2 ? d2 : d3;
    const ushort* rk = ty == 0 ? rk0 : ty == 1 ? rk1 : ty == 2 ? rk2 : rk3;
    const int* rp = ty == 0 ? r0 : ty == 1 ? r1 : ty == 2 ? r2 : r3;
    const unsigned char* ho = ty == 0 ? h0 : ty == 1 ? h1 : ty == 2 ? h2 : h3;
    ushort* out = ty == 0 ? o0 : ty == 1 ? o1 : ty == 2 ? o2 : o3;
    const int dd = dst[e];
    out[rp[dd] + (int)ho[(size_t)c * NN + dd] + (int)rk[e]] =
        (ushort)src[e];
  }
}

// ---------------------------------------------------------------------------
// Combined dual-type gather, QUAD-NODE layout (r11): 4 nodes/wave, 16
// lanes/node, one sequential edge stream per half; epilogue = one
// shfl_xor(8). Sequential node walk (r14's degree-sort perm regressed:
// locality of es/rp reads + output rows beats lane-idle reduction).
__global__ __launch_bounds__(256) void gat_gather_all(
    const int* __restrict__ rp0, const ushort* __restrict__ ss0,
    const int* __restrict__ rp1, const ushort* __restrict__ ss1,
    const int* __restrict__ rp2, const ushort* __restrict__ ss2,
    const int* __restrict__ rp3, const ushort* __restrict__ ss3,
    const float* __restrict__ esE0, const unsigned char* __restrict__ hsE0,
    const float* __restrict__ esE1, const unsigned char* __restrict__ hsE1,
    const float* __restrict__ esP3, const unsigned char* __restrict__ hsP3,
    const float* __restrict__ esP2, const unsigned char* __restrict__ hsP2,
    const float* __restrict__ edEA, const float* __restrict__ edEB,
    const float* __restrict__ edPA, const float* __restrict__ edPB,
    const float* __restrict__ bias, int l, ushort* __restrict__ outxe,
    ushort* __restrict__ outxp, int to_csum, float* __restrict__ csum_rep) {
  const int lane = threadIdx.x & 63;
  const int wv = threadIdx.x >> 6;
  const int half = (lane >> 3) & 1;
  const int sub = lane & 7;
  const int wid = (blockIdx.x * 256 + threadIdx.x) >> 4;  // global node slot
  const bool active = wid < NE_N + NP_N;

  const float *b0 = bias, *b1 = bias;
  ushort* outb = outxe;
  int node = 0;
  int beg = 0, end = 0;
  const ushort* ss = ss0;
  const float* es = esE0;
  const unsigned char* hs = hsE0;
  float edv = 0.f;

  if (active) {
    if (wid < NE_N) {  // e-dst: ee (half 0) + pe (half 1)
      node = wid;
      if (half == 0) { ss = ss0; es = esE0; hs = hsE0; edv = edEA[node];
                       beg = rp0[node]; end = rp0[node + 1]; }
      else           { ss = ss3; es = esP3; hs = hsP3; edv = edEB[node];
                       beg = rp3[node]; end = rp3[node + 1]; }
      b0 = bias + (l * 4 + 0) * DIM; b1 = bias + (l * 4 + 3) * DIM;
      outb = outxe;
    } else {  // p-dst: ep (half 0) + pp (half 1)
      node = wid - NE_N;
      if (half == 0) { ss = ss1; es = esE1; hs = hsE1; edv = edPA[node];
                       beg = rp1[node]; end = rp1[node + 1]; }
      else           { ss = ss2; es = esP2; hs = hsP2; edv = edPB[node];
                       beg = rp2[node]; end = rp2[node + 1]; }
      b0 = bias + (l * 4 + 1) * DIM; b1 = bias + (l * 4 + 2) * DIM;
      outb = outxp;
    }
  }

  f32x2 acc2[8];
#pragma unroll
  for (int j = 0; j < 8; j++) acc2[j] = (f32x2){0.f, 0.f};
  float sw = 0.f;

  // one-deep pipelined gather loop
  float esC = 0.f;
  uint4 hC = make_uint4(0, 0, 0, 0);
  if (beg < end) {
    const int s0v = ss[beg];
    esC = es[s0v];
    hC = *(const uint4*)&hs[(size_t)s0v * DIM + sub * 16];
  }
  for (int e = beg; e < end; e++) {
    const int en = (e + 1 < end) ? e + 1 : e;
    const int sn = ss[en];
    const float esN = es[sn];
    const uint4 hN = *(const uint4*)&hs[(size_t)sn * DIM + sub * 16];

    const float w = exp2f(fmaxf(esC + edv, 0.f));
    sw += w;
    const f32x2 w2 = {w, w};
    acc2[0] += w2 * __builtin_amdgcn_cvt_pk_f32_fp8((int)hC.x, false);
    acc2[1] += w2 * __builtin_amdgcn_cvt_pk_f32_fp8((int)hC.x, true);
    acc2[2] += w2 * __builtin_amdgcn_cvt_pk_f32_fp8((int)hC.y, false);
    acc2[3] += w2 * __builtin_amdgcn_cvt_pk_f32_fp8((int)hC.y, true);
    acc2[4] += w2 * __builtin_amdgcn_cvt_pk_f32_fp8((int)hC.z, false);
    acc2[5] += w2 * __builtin_amdgcn_cvt_pk_f32_fp8((int)hC.z, true);
    acc2[6] += w2 * __builtin_amdgcn_cvt_pk_f32_fp8((int)hC.w, false);
    acc2[7] += w2 * __builtin_amdgcn_cvt_pk_f32_fp8((int)hC.w, true);
    esC = esN;
    hC = hN;
  }

  // sw is lane-local (single stream); normalize, then cross-half combine
  const float inv = 1.f / fmaxf(sw, 1e-16f);
#pragma unroll
  for (int j = 0; j < 8; j++) {
    acc2[j].x *= inv;
    acc2[j].y *= inv;
    f32x2 t;
    t.x = __shfl_xor(acc2[j].x, 8, 64);
    t.y = __shfl_xor(acc2[j].y, 8, 64);
    acc2[j] += t;
  }

  if (to_csum) {
    // cross-quad combine: every lane ends with the 4-node sum for its cols
#pragma unroll
    for (int j = 0; j < 8; j++) {
      f32x2 t;
      t.x = __shfl_xor(acc2[j].x, 16, 64);
      t.y = __shfl_xor(acc2[j].y, 16, 64);
      acc2[j] += t;
      t.x = __shfl_xor(acc2[j].x, 32, 64);
      t.y = __shfl_xor(acc2[j].y, 32, 64);
      acc2[j] += t;
    }
    __shared__ float lsum[4][DIM];
    if (lane < 8) {  // quad 0, half 0: covers all 128 cols across 8 subs
#pragma unroll
      for (int j = 0; j < 8; j++)
        *(float2*)&lsum[wv][sub * 16 + 2 * j] =
            make_float2(acc2[j].x, acc2[j].y);
    }
    __syncthreads();
    if (threadIdx.x < DIM) {
      float s = lsum[0][threadIdx.x] + lsum[1][threadIdx.x] +
                lsum[2][threadIdx.x] + lsum[3][threadIdx.x];
      float* rep = csum_rep + (size_t)(blockIdx.x & (NREP - 1)) * DIM;
      unsafeAtomicAdd(&rep[threadIdx.x], s);
    }
  } else if (active && half == 0) {
    // lane owns cols [sub*16, sub*16+16): assemble 32B (2x uint4) row slice
    unsigned ow[8];
#pragma unroll
    for (int j = 0; j < 8; j++) {
      const int d = sub * 16 + 2 * j;
      float2 bb0 = *(const float2*)&b0[d];
      float2 bb1 = *(const float2*)&b1[d];
      unsigned lo = f2bf(acc2[j].x + bb0.x + bb1.x);
      unsigned hi = f2bf(acc2[j].y + bb0.y + bb1.y);
      ow[j] = lo | (hi << 16);
    }
    uint4* op = (uint4*)&outb[(size_t)node * DIM + sub * 16];
    op[0] = make_uint4(ow[0], ow[1], ow[2], ow[3]);
    op[1] = make_uint4(ow[4], ow[5], ow[6], ow[7]);
  }
}

// ---------------------------------------------------------------------------
// final: reduce NREP csum replicas, add analytic bias term, project.
__global__ __launch_bounds__(512) void final_proj(
    const float* __restrict__ csum_rep, const float* __restrict__ bias,
    const float* __restrict__ lin_W, const float* __restrict__ lin_b,
    float* __restrict__ out) {
  __shared__ float parts[4][DIM];
  __shared__ float col[DIM];
  const int k = threadIdx.x & 127;   // column
  const int pt = threadIdx.x >> 7;   // replica partition 0..3
  float s = 0.f;
#pragma unroll 8
  for (int r = pt * (NREP / 4); r < (pt + 1) * (NREP / 4); r++)
    s += csum_rep[(size_t)r * DIM + k];
  parts[pt][k] = s;
  __syncthreads();
  if (threadIdx.x < DIM) {
    const float* bE0 = bias + (2 * 4 + 0) * DIM;
    const float* bE1 = bias + (2 * 4 + 3) * DIM;
    const float* bP0 = bias + (2 * 4 + 1) * DIM;
    const float* bP1 = bias + (2 * 4 + 2) * DIM;
    col[k] = parts[0][k] + parts[1][k] + parts[2][k] + parts[3][k] +
             (float)NE_N * (bE0[k] + bE1[k]) +
             (float)NP_N * (bP0[k] + bP1[k]);
  }
  __syncthreads();
  if (threadIdx.x < 2) {
    float acc = 0.f;
#pragma unroll 8
    for (int j = 0; j < DIM; j++) acc += col[j] * lin_W[j * 2 + threadIdx.x];
    out[threadIdx.x] = acc / (float)(NE_N + NP_N) + lin_b[threadIdx.x];
  }
}

// ---------------------------------------------------------------------------
extern "C" void kernel_launch(void* const* d_in, const int* in_sizes, int n_in,
                              void* d_out, int out_size, void* d_ws,
                              size_t ws_size, hipStream_t stream) {
  const float* x_elem  = (const float*)d_in[0];
  const float* x_proc  = (const float*)d_in[1];
  const float* W_src   = (const float*)d_in[2];
  const float* W_dst   = (const float*)d_in[3];
  const float* att_src = (const float*)d_in[4];
  const float* att_dst = (const float*)d_in[5];
  const float* bias    = (const float*)d_in[6];
  const float* lin_W   = (const float*)d_in[7];
  const float* lin_b   = (const float*)d_in[8];
  const int* esrc[4] = {(const int*)d_in[9],  (const int*)d_in[11],
                        (const int*)d_in[13], (const int*)d_in[15]};
  const int* edst[4] = {(const int*)d_in[10], (const int*)d_in[12],
                        (const int*)d_in[14], (const int*)d_in[16]};

  // ---- workspace carve-up (16B-aligned chunks) ----
  char* p = (char*)d_ws;
  ushort* xe_bf[2]; ushort* xp_bf[2];
  xe_bf[0] = (ushort*)p; p += (size_t)NE_N * DIM * 2;
  xe_bf[1] = (ushort*)p; p += (size_t)NE_N * DIM * 2;
  xp_bf[0] = (ushort*)p; p += (size_t)NP_N * DIM * 2;
  xp_bf[1] = (ushort*)p; p += (size_t)NP_N * DIM * 2;
  unsigned char* hsE0 = (unsigned char*)p; p += (size_t)NE_N * DIM;  // W[l,0]
  unsigned char* hsE1 = (unsigned char*)p; p += (size_t)NE_N * DIM;  // W[l,1]
  unsigned char* hsP3 = (unsigned char*)p; p += (size_t)NP_N * DIM;  // W[l,3]
  unsigned char* hsP2 = (unsigned char*)p; p += (size_t)NP_N * DIM;  // W[l,2]
  ushort* WbT = (ushort*)p; p += (size_t)12 * DIM * DIM * 2;
  float* esE0 = (float*)p; p += (size_t)NE_N * 4;
  float* esE1 = (float*)p; p += (size_t)NE_N * 4;
  float* esP3 = (float*)p; p += (size_t)NP_N * 4;
  float* esP2 = (float*)p; p += (size_t)NP_N * 4;
  float* edEA = (float*)p; p += (size_t)NE_N * 4;
  float* edEB = (float*)p; p += (size_t)NE_N * 4;
  float* edPA = (float*)p; p += (size_t)NP_N * 4;
  float* edPB = (float*)p; p += (size_t)NP_N * 4;
  float* vec = (float*)p; p += 12 * DIM * 4;
  int* parti = (int*)p; p += 4 * 64 * 4;
  // csum_rep + chunk-hist arrays contiguous -> single memset
  float* csum_rep = (float*)p; p += (size_t)NREP * DIM * 4;
  unsigned char* hh[4];
  hh[0] = (unsigned char*)p; p += (size_t)NE_N * NCHK;
  hh[1] = (unsigned char*)p; p += (size_t)NP_N * NCHK;
  hh[2] = (unsigned char*)p; p += (size_t)NP_N * NCHK;
  hh[3] = (unsigned char*)p; p += (size_t)NE_N * NCHK;
  int* cnt[4];
  for (int t = 0; t < 4; t++) { cnt[t] = (int*)p; p += (NE_N + 4) * 4; }
  int* rp[4];
  for (int t = 0; t < 4; t++) { rp[t] = (int*)p; p += (NE_N + 4) * 4; }
  ushort* ssrc[4];
  for (int t = 0; t < 4; t++) { ssrc[t] = (ushort*)p; p += (size_t)E_N * 2; }
  ushort* rank[4];
  for (int t = 0; t < 4; t++) { rank[t] = (ushort*)p; p += (size_t)E_N * 2; }

  // ---- zero csum replicas + chunk hists in one memset ----
  hipMemsetAsync(csum_rep, 0,
                 (size_t)NREP * DIM * 4 +
                     (size_t)(2 * NE_N + 2 * NP_N) * NCHK,
                 stream);

  // ---- fused: LDS-hash rank build | conv_w | vec (no device atomics) ----
  hist_setup_k<<<HS_TOT, 512, 0, stream>>>(
      W_src, W_dst, att_dst, WbT, vec, edst[0], edst[1], edst[2], edst[3],
      hh[0], hh[1], hh[2], hh[3], rank[0], rank[1], rank[2], rank[3]);

  // ---- scan: chunk-offset prefix + cnt (A), rp writeback (BC) ----
  scanA_k<<<dim3(49, 4), 256, 0, stream>>>(hh[0], hh[1], hh[2], hh[3],
                                           cnt[0], cnt[1], cnt[2], cnt[3],
                                           parti);
  scanBC_k<<<dim3(49, 4), 256, 0, stream>>>(cnt[0], cnt[1], cnt[2], cnt[3],
                                            rp[0], rp[1], rp[2], rp[3], parti);

  // ---- layer-0 gemm (first, long-running) + XCD-affine atomic-free fill ----
  fill_gemm0_k<<<HG2_TOT, 512, 0, stream>>>(
      x_elem, x_proc, WbT, att_src, vec, hsE0, hsE1, hsP3, hsP2, esE0, esE1,
      esP3, esP2, edEA, edEB, edPA, edPB, esrc[0], esrc[1], esrc[2], esrc[3],
      edst[0], edst[1], edst[2], edst[3], rank[0], rank[1], rank[2], rank[3],
      rp[0], rp[1], rp[2], rp[3], hh[0], hh[1], hh[2], hh[3],
      ssrc[0], ssrc[1], ssrc[2], ssrc[3]);

  // ---- layers ----
  int c = 0;
  for (int l = 0; l < 3; l++) {
    if (l > 0) {
      gemm_k<<<GEMM_BLK, 512, 0, stream>>>(
          xe_bf[c], xp_bf[c], WbT, att_src, vec, l, hsE0, hsE1, hsP3, hsP2,
          esE0, esE1, esP3, esP2, edEA, edEB, edPA, edPB);
    }
    int to_csum = (l == 2) ? 1 : 0;
    gat_gather_all<<<(NE_N + NP_N + 15) / 16, 256, 0, stream>>>(
        rp[0], ssrc[0], rp[1], ssrc[1], rp[2], ssrc[2], rp[3], ssrc[3], esE0,
        hsE0, esE1, hsE1, esP3, hsP3, esP2, hsP2, edEA, edEB, edPA, edPB,
        bias, l, xe_bf[1 - c], xp_bf[1 - c], to_csum, csum_rep);
    c = 1 - c;
  }

  final_proj<<<1, 512, 0, stream>>>(csum_rep, bias, lin_W, lin_b,
                                    (float*)d_out);
}